// Round 10
// baseline (62.744 us; speedup 1.0000x reference)
//
#include <hip/hip_runtime.h>

#define NBINS 100
#define NROWS 101          // row 100 = spill slot for x -> 1.0 boundary (discarded)
#define BLK   64           // one wave per block; column == lane (exclusive)
#define GRID  1536         // 6 blocks/CU (LDS ~25.9 KB/block)
#define REP   8            // global accumulator replicas (atomic contention relief)

typedef unsigned int       u32;
typedef unsigned long long u64;

// Per-element: u = round(x*102400) -> k = u>>10 (bin), ti = u&1023 (frac 1/1024).
// Column cell (u32): (N << 20) + sum(ti).  Per-lane <=683 elems -> T < 2^20.
// Global cell (u64): (N << 37) + T_total.  Exact integer accumulation.
// count[b] = 0.01 * (N_b + (T_{b-1} - T_b)/1024);  out = count / (sum + 1e-6).

__global__ void histo_zero(u64* __restrict__ g) {
    int i = blockIdx.x * blockDim.x + threadIdx.x;
    if (i < REP * NBINS) g[i] = 0ull;
}

__global__ __launch_bounds__(BLK) void histo_accum(const float* __restrict__ x,
                                                   u64* __restrict__ g,
                                                   int n4, int n) {
    __shared__ u32 h[NROWS * BLK];
    const int lane = threadIdx.x;

    for (int i = lane; i < NROWS * BLK; i += BLK) h[i] = 0u;
    __syncthreads();

// G=4 batch: one float4 -> 4 ds_reads, ONE lgkmcnt stall, 4 adds, 4 ds_writes.
// (R6's G=2 had one stall per 2 elements; the ~130-cyc DS-latency stall is the
// measured limiter at 6 waves/CU.)  Duplicate bins among the 4 are merged
// exactly in registers first — ordered pair chain (0,1)(0,2)(0,3)(1,2)(1,3)
// (2,3) pushes weight onto the LAST occurrence, and DS FIFO order makes the
// last write win. Merge VALU hides under the ds_read latency.
#define MRG(ii, jj) { bool e = (k##ii == k##jj);               \
                      w##jj += e ? w##ii : 0u;                 \
                      w##ii  = e ? 0u : w##ii; }

#define PROC4(v) {                                             \
        u32 u0 = (u32)((v).x * 102400.0f + 0.5f);              \
        u32 u1 = (u32)((v).y * 102400.0f + 0.5f);              \
        u32 u2 = (u32)((v).z * 102400.0f + 0.5f);              \
        u32 u3 = (u32)((v).w * 102400.0f + 0.5f);              \
        u32 k0 = u0 >> 10, k1 = u1 >> 10;                      \
        u32 k2 = u2 >> 10, k3 = u3 >> 10;                      \
        u32 w0 = (1u << 20) | (u0 & 1023u);                    \
        u32 w1 = (1u << 20) | (u1 & 1023u);                    \
        u32 w2 = (1u << 20) | (u2 & 1023u);                    \
        u32 w3 = (1u << 20) | (u3 & 1023u);                    \
        MRG(0, 1); MRG(0, 2); MRG(0, 3);                       \
        MRG(1, 2); MRG(1, 3); MRG(2, 3);                       \
        int a0 = (int)(k0 * BLK) + lane;                       \
        int a1 = (int)(k1 * BLK) + lane;                       \
        int a2 = (int)(k2 * BLK) + lane;                       \
        int a3 = (int)(k3 * BLK) + lane;                       \
        u32 d0 = h[a0];                                        \
        u32 d1 = h[a1];                                        \
        u32 d2 = h[a2];                                        \
        u32 d3 = h[a3];                                        \
        h[a0] = d0 + w0;                                       \
        h[a1] = d1 + w1;                                       \
        h[a2] = d2 + w2;                                       \
        h[a3] = d3 + w3;                                       \
    }

#define PROC1(va) {                                            \
        u32 u0 = (u32)((va) * 102400.0f + 0.5f);               \
        u32 k0 = u0 >> 10;                                     \
        int a0 = (int)(k0 * BLK) + lane;                       \
        h[a0] += (1u << 20) + (u0 & 1023u);                    \
    }

    const float4* __restrict__ x4 = (const float4*)x;
    const int stride = gridDim.x * BLK;
    int i = blockIdx.x * BLK + lane;

    // R6-proven loop shape: 8 float4 loads in flight per lane; compiler
    // schedules loads ahead of the DS chains on its own (R9 showed explicit
    // pinning doesn't help).
    for (; i + 7 * stride < n4; i += 8 * stride) {
        float4 v0 = x4[i];
        float4 v1 = x4[i + 1 * stride];
        float4 v2 = x4[i + 2 * stride];
        float4 v3 = x4[i + 3 * stride];
        float4 v4 = x4[i + 4 * stride];
        float4 v5 = x4[i + 5 * stride];
        float4 v6 = x4[i + 6 * stride];
        float4 v7 = x4[i + 7 * stride];
        PROC4(v0); PROC4(v1); PROC4(v2); PROC4(v3);
        PROC4(v4); PROC4(v5); PROC4(v6); PROC4(v7);
    }
    for (; i < n4; i += stride) {
        float4 v = x4[i];
        PROC4(v);
    }
    if (blockIdx.x == 0) {               // scalar tail (n % 4)
        for (int t = n4 * 4 + lane; t < n; t += BLK) { float v = x[t]; PROC1(v); }
    }
#undef PROC4
#undef PROC1
#undef MRG

    __syncthreads();

    // Reduce 64 columns/bin (diagonal sweep: bank = (c+lane)%32, 2-way = free),
    // one packed-u64 global atomic per bin per block (8 replicas).
    u64* grep = &g[(blockIdx.x & (REP - 1)) * NBINS];
    for (int b = lane; b < NBINS; b += BLK) {
        u32 Ns = 0, Ts = 0;
#pragma unroll
        for (int c = 0; c < BLK; ++c) {
            int cc = (c + lane) & (BLK - 1);
            u32 u = h[b * BLK + cc];
            Ns += u >> 20;
            Ts += u & 0xFFFFFu;
        }
        atomicAdd(&grep[b], ((u64)Ns << 37) + (u64)Ts);
    }
}

__global__ void histo_final(const u64* __restrict__ g, float* __restrict__ out) {
    __shared__ float Tprev[NBINS + 1];
    __shared__ float wsum[2];
    const int t = threadIdx.x;           // 128 threads = 2 waves

    float N = 0.0f, T = 0.0f;
    if (t < NBINS) {
        u64 acc = 0ull;
#pragma unroll
        for (int r = 0; r < REP; ++r) acc += g[r * NBINS + t];
        N = (float)(acc >> 37);
        T = (float)(acc & ((1ull << 37) - 1ull));
        Tprev[t + 1] = T;
    }
    if (t == 127) Tprev[0] = 0.0f;
    __syncthreads();

    float c = 0.0f;
    if (t < NBINS) c = 0.01f * (N + (Tprev[t] - T) * (1.0f / 1024.0f));

    float s = c;
#pragma unroll
    for (int o = 32; o > 0; o >>= 1) s += __shfl_down(s, o, 64);
    if ((t & 63) == 0) wsum[t >> 6] = s;
    __syncthreads();

    float total = wsum[0] + wsum[1];
    if (t < NBINS) out[t] = c / (total + 1e-6f);
}

extern "C" void kernel_launch(void* const* d_in, const int* in_sizes, int n_in,
                              void* d_out, int out_size, void* d_ws, size_t ws_size,
                              hipStream_t stream) {
    const float* x   = (const float*)d_in[0];  // [64 * 1048576] fp32 in [0,1)
    float*       out = (float*)d_out;          // [100] fp32
    u64*         g   = (u64*)d_ws;             // REP*100 u64 accumulators

    const int n  = in_sizes[0];
    const int n4 = n / 4;

    histo_zero<<<(REP * NBINS + 255) / 256, 256, 0, stream>>>(g);

    int blocks = GRID;
    int need   = (n4 + BLK - 1) / BLK;
    if (blocks > need) blocks = need;
    histo_accum<<<blocks, BLK, 0, stream>>>(x, g, n4, n);

    histo_final<<<1, 128, 0, stream>>>(g, out);
}

// Round 11
// 58.219 us; speedup vs baseline: 1.0777x; 1.0777x over previous
//
#include <hip/hip_runtime.h>

#define NBINS 100
#define NROWS 101          // row 100 = spill slot for x -> 1.0 boundary (discarded)
#define BLK   64           // one wave per block; column == lane (exclusive)
#define GRID  1536         // 6 blocks/CU (LDS ~25.9 KB/block)
#define REP   8            // global accumulator replicas (atomic contention relief)

typedef unsigned int       u32;
typedef unsigned long long u64;

// Per-element: u = round(x*102400) -> k = u>>10 (bin), ti = u&1023 (frac 1/1024).
// Column cell (u32): (N << 20) + sum(ti).  Per-lane <=~683 elems -> T < 2^20.
// Global cell (u64): (N << 37) + T_total.  Exact integer accumulation.
// count[b] = 0.01 * (N_b + (T_{b-1} - T_b)/1024);  out = count / (sum + 1e-6).

__global__ void histo_zero(u64* __restrict__ g) {
    int i = blockIdx.x * blockDim.x + threadIdx.x;
    if (i < REP * NBINS) g[i] = 0ull;
}

__global__ __launch_bounds__(BLK) void histo_accum(const float* __restrict__ x,
                                                   u64* __restrict__ g,
                                                   int n4, int n, int chunk) {
    __shared__ u32 h[NROWS * BLK];
    const int lane = threadIdx.x;

    for (int i = lane; i < NROWS * BLK; i += BLK) h[i] = 0u;
    __syncthreads();

// R6's proven G=2 batch: both reads issue before either write; same-bin
// collision merged in registers ("last write wins" on the merged weight).
#define PROC2(va, vb) {                                        \
        u32 u0 = (u32)((va) * 102400.0f + 0.5f);               \
        u32 u1 = (u32)((vb) * 102400.0f + 0.5f);               \
        u32 k0 = u0 >> 10, k1 = u1 >> 10;                      \
        u32 w0 = (1u << 20) + (u0 & 1023u);                    \
        u32 w1 = (1u << 20) + (u1 & 1023u);                    \
        bool eq = (k0 == k1);                                  \
        u32 w1m = w1 + (eq ? w0 : 0u);                         \
        u32 w0m = eq ? 0u : w0;                                \
        int a0 = (int)(k0 * BLK) + lane;                       \
        int a1 = (int)(k1 * BLK) + lane;                       \
        u32 d0 = h[a0];                                        \
        u32 d1 = h[a1];                                        \
        h[a0] = d0 + w0m;                                      \
        h[a1] = d1 + w1m;                                      \
    }

#define PROC1(va) {                                            \
        u32 u0 = (u32)((va) * 102400.0f + 0.5f);               \
        u32 k0 = u0 >> 10;                                     \
        int a0 = (int)(k0 * BLK) + lane;                       \
        h[a0] += (1u << 20) + (u0 & 1023u);                    \
    }

#define PROC2x2(v) { PROC2((v).x, (v).y); PROC2((v).z, (v).w); }

    const float4* __restrict__ x4 = (const float4*)x;

    // Block-contiguous chunk (THE one change vs R6): block b owns float4s
    // [b*chunk, min((b+1)*chunk, n4)). Its 8 in-flight loads are consecutive
    // 1 KB lines -> 8 KB sequential per wave-iteration (DRAM-row friendly),
    // vs grid-stride's 1.57 MB jumps per load.
    const int base = blockIdx.x * chunk;
    const int end  = min(base + chunk, n4);
    const int nfull = (end - base) / (8 * BLK);

    for (int j = 0; j < nfull; ++j) {
        int i = base + j * (8 * BLK) + lane;
        float4 v0 = x4[i];
        float4 v1 = x4[i + 1 * BLK];
        float4 v2 = x4[i + 2 * BLK];
        float4 v3 = x4[i + 3 * BLK];
        float4 v4 = x4[i + 4 * BLK];
        float4 v5 = x4[i + 5 * BLK];
        float4 v6 = x4[i + 6 * BLK];
        float4 v7 = x4[i + 7 * BLK];
        PROC2x2(v0); PROC2x2(v1); PROC2x2(v2); PROC2x2(v3);
        PROC2x2(v4); PROC2x2(v5); PROC2x2(v6); PROC2x2(v7);
    }
    for (int i = base + nfull * (8 * BLK) + lane; i < end; i += BLK) {
        float4 v = x4[i];
        PROC2x2(v);
    }
    if (blockIdx.x == 0) {               // scalar tail (n % 4)
        for (int t = n4 * 4 + lane; t < n; t += BLK) { float v = x[t]; PROC1(v); }
    }
#undef PROC2x2
#undef PROC1
#undef PROC2

    __syncthreads();

    // Reduce 64 columns/bin (diagonal sweep: bank = (c+lane)%32, 2-way = free),
    // one packed-u64 global atomic per bin per block (8 replicas).
    u64* grep = &g[(blockIdx.x & (REP - 1)) * NBINS];
    for (int b = lane; b < NBINS; b += BLK) {
        u32 Ns = 0, Ts = 0;
#pragma unroll
        for (int c = 0; c < BLK; ++c) {
            int cc = (c + lane) & (BLK - 1);
            u32 u = h[b * BLK + cc];
            Ns += u >> 20;
            Ts += u & 0xFFFFFu;
        }
        atomicAdd(&grep[b], ((u64)Ns << 37) + (u64)Ts);
    }
}

__global__ void histo_final(const u64* __restrict__ g, float* __restrict__ out) {
    __shared__ float Tprev[NBINS + 1];
    __shared__ float wsum[2];
    const int t = threadIdx.x;           // 128 threads = 2 waves

    float N = 0.0f, T = 0.0f;
    if (t < NBINS) {
        u64 acc = 0ull;
#pragma unroll
        for (int r = 0; r < REP; ++r) acc += g[r * NBINS + t];
        N = (float)(acc >> 37);
        T = (float)(acc & ((1ull << 37) - 1ull));
        Tprev[t + 1] = T;
    }
    if (t == 127) Tprev[0] = 0.0f;
    __syncthreads();

    float c = 0.0f;
    if (t < NBINS) c = 0.01f * (N + (Tprev[t] - T) * (1.0f / 1024.0f));

    float s = c;
#pragma unroll
    for (int o = 32; o > 0; o >>= 1) s += __shfl_down(s, o, 64);
    if ((t & 63) == 0) wsum[t >> 6] = s;
    __syncthreads();

    float total = wsum[0] + wsum[1];
    if (t < NBINS) out[t] = c / (total + 1e-6f);
}

extern "C" void kernel_launch(void* const* d_in, const int* in_sizes, int n_in,
                              void* d_out, int out_size, void* d_ws, size_t ws_size,
                              hipStream_t stream) {
    const float* x   = (const float*)d_in[0];  // [64 * 1048576] fp32 in [0,1)
    float*       out = (float*)d_out;          // [100] fp32
    u64*         g   = (u64*)d_ws;             // REP*100 u64 accumulators

    const int n  = in_sizes[0];
    const int n4 = n / 4;

    histo_zero<<<(REP * NBINS + 255) / 256, 256, 0, stream>>>(g);

    int blocks = GRID;
    int need   = (n4 + BLK - 1) / BLK;
    if (blocks > need) blocks = need;
    int chunk  = (n4 + blocks - 1) / blocks;
    histo_accum<<<blocks, BLK, 0, stream>>>(x, g, n4, n, chunk);

    histo_final<<<1, 128, 0, stream>>>(g, out);
}